// Round 1
// baseline (314.212 us; speedup 1.0000x reference)
//
#include <hip/hip_runtime.h>
#include <cstdint>
#include <cstddef>

#define N_NODES 100000
#define N_EDGES 1600000
#define IN_DIM  256
#define OUT_DIM 128

#define BSHIFT 7
#define BNODES 128       // nodes per bucket
#define NBUCK  782       // ceil(N_NODES / 128)
#define BCAP   3200      // slots per bucket (mean ~2240 padded, ~17 sigma headroom)
#define MAXE   13        // ceil(BCAP / 256) edges per thread in bucket_k
#define EPB    2048      // edges per partition block

#define ENC_NEG_INF 0x00800000u   // encode(-FLT_MAX)

typedef __attribute__((ext_vector_type(8))) short bf16x8;
typedef __attribute__((ext_vector_type(4))) float f32x4;

__device__ __forceinline__ unsigned bf16rn(float f) {
    unsigned u = __float_as_uint(f);
    return (u + 0x7FFFu + ((u >> 16) & 1u)) >> 16;
}

// ---------------- W -> bf16 fragment order (paired-dim swizzle) + cursor init ----
// dim(c, n) = (c>>1)*32 + 2*n + (c&1): lane col owns dim pairs {32g+2col, 32g+2col+1}
// in acc[2g], acc[2g+1] -> dword z16 stores in the gemm epilogue.
__global__ void w16s_k(const float* __restrict__ W, unsigned short* __restrict__ w16s,
                       int* __restrict__ bucket_cursor)
{
    int t = blockIdx.x * blockDim.x + threadIdx.x;
    if (t < NBUCK) bucket_cursor[t] = 0;
    if (t >= IN_DIM * OUT_DIM) return;
    int j  = t & 7;
    int n  = (t >> 3) & 15;
    int q  = (t >> 7) & 3;
    int c  = (t >> 9) & 7;
    int kc = t >> 12;
    int k   = kc * 32 + q * 8 + j;
    int dim = (c >> 1) * 32 + n * 2 + (c & 1);
    w16s[t] = (unsigned short)bf16rn(W[k * OUT_DIM + dim]);
}

// ---------------- MFMA GEMM: z16 = bf16(h @ W), el/er fused ----------------
#define LA_STRIDE 264

__global__ __launch_bounds__(256) void gemm_z_k(
    const float* __restrict__ h, const unsigned short* __restrict__ w16s,
    const float* __restrict__ a,
    unsigned short* __restrict__ z16, float* __restrict__ el, float* __restrict__ er)
{
    __shared__ unsigned short lA[64 * LA_STRIDE];
    const int t  = threadIdx.x;
    const int n0 = blockIdx.x * 64;

    #pragma unroll
    for (int p = 0; p < 16; ++p) {
        int f = p * 256 + t;
        int i = f >> 6;
        int col = (f & 63) * 4;
        float4 v = make_float4(0.f, 0.f, 0.f, 0.f);
        if (n0 + i < N_NODES)
            v = *(const float4*)&h[(size_t)(n0 + i) * IN_DIM + col];
        uint2 pk;
        pk.x = bf16rn(v.x) | (bf16rn(v.y) << 16);
        pk.y = bf16rn(v.z) | (bf16rn(v.w) << 16);
        *(uint2*)&lA[i * LA_STRIDE + col] = pk;
    }
    __syncthreads();

    const int w    = t >> 6;
    const int lane = t & 63;
    const int q    = lane >> 4;
    const int col  = lane & 15;

    f32x4 acc[8];
    #pragma unroll
    for (int c = 0; c < 8; ++c) acc[c] = (f32x4){0.f, 0.f, 0.f, 0.f};

    #pragma unroll
    for (int kc = 0; kc < 8; ++kc) {
        bf16x8 af = *(const bf16x8*)&lA[(w * 16 + col) * LA_STRIDE + kc * 32 + q * 8];
        bf16x8 bfr[8];
        #pragma unroll
        for (int c = 0; c < 8; ++c)
            bfr[c] = *(const bf16x8*)&w16s[((((kc * 8 + c) * 4 + q) * 16) + col) * 8];
        #pragma unroll
        for (int c = 0; c < 8; ++c)
            acc[c] = __builtin_amdgcn_mfma_f32_16x16x32_bf16(af, bfr[c], acc[c], 0, 0, 0);
    }

    float aL[8], aR[8];
    #pragma unroll
    for (int c = 0; c < 8; ++c) {
        int dim = (c >> 1) * 32 + col * 2 + (c & 1);
        aL[c] = a[dim];
        aR[c] = a[128 + dim];
    }
    #pragma unroll
    for (int r = 0; r < 4; ++r) {
        int node = n0 + w * 16 + q * 4 + r;
        float sl = 0.f, sr = 0.f;
        #pragma unroll
        for (int c = 0; c < 8; ++c) {
            sl += acc[c][r] * aL[c];
            sr += acc[c][r] * aR[c];
        }
        #pragma unroll
        for (int o = 1; o < 16; o <<= 1) {
            sl += __shfl_xor(sl, o, 64);
            sr += __shfl_xor(sr, o, 64);
        }
        if (node < N_NODES) {
            #pragma unroll
            for (int g = 0; g < 4; ++g) {
                unsigned u = bf16rn(acc[2 * g][r]) | (bf16rn(acc[2 * g + 1][r]) << 16);
                ((unsigned*)z16)[(size_t)node * 64 + g * 16 + col] = u;
            }
            if (col == 0) { el[node] = sl; er[node] = sr; }
        }
    }
}

// ---------------- phase 1: partition edges into dst-buckets ----------------
// ebuf entry: [e:32][free:8][src:17][localdst:7]
__global__ __launch_bounds__(256) void partition_k(
    const int* __restrict__ src, const int* __restrict__ dst,
    const float* __restrict__ el, const float* __restrict__ er,
    int* __restrict__ bucket_cursor, unsigned long long* __restrict__ ebuf)
{
    __shared__ int hist[NBUCK];
    __shared__ int gbaseL[NBUCK];
    const int t = threadIdx.x;
    for (int i = t; i < NBUCK; i += 256) hist[i] = 0;
    __syncthreads();

    const int e0 = blockIdx.x * EPB;
    int bucks[8], ranks[8];
    unsigned long long pk[8];
    #pragma unroll
    for (int k = 0; k < 8; ++k) {
        int e = e0 + k * 256 + t;
        bucks[k] = -1;
        if (e < N_EDGES) {
            int s = src[e], d = dst[e];
            float v = el[s] + er[d];
            v = (v > 0.0f) ? v : 0.01f * v;   // leaky_relu slope 0.01
            int b = d >> BSHIFT;
            bucks[k] = b;
            ranks[k] = atomicAdd(&hist[b], 1);
            pk[k] = ((unsigned long long)__float_as_uint(v) << 32)
                  | ((unsigned)s << BSHIFT) | (unsigned)(d & (BNODES - 1));
        }
    }
    __syncthreads();
    for (int i = t; i < NBUCK; i += 256) {
        int hc = hist[i];
        gbaseL[i] = hc ? atomicAdd(&bucket_cursor[i], hc) : 0;
    }
    __syncthreads();
    #pragma unroll
    for (int k = 0; k < 8; ++k)
        if (bucks[k] >= 0)
            ebuf[(size_t)bucks[k] * BCAP + gbaseL[bucks[k]] + ranks[k]] = pk[k];
}

// ---------------- phase 2: per-bucket softmax weights + fine sort ------------
// Single ebuf read: edges live in registers between the histogram/max pass and
// the placement pass; rank is captured from the deg atomicAdd (no cur atomic,
// no denom atomic - denom is summed inline in node_pass_k).
// perm entry: [w:32][src:32] with w = exp(e - emax); pads w=0.
__global__ __launch_bounds__(256) void bucket_k(
    const int* __restrict__ bucket_cursor, const unsigned long long* __restrict__ ebuf,
    unsigned long long* __restrict__ perm, int* __restrict__ begA, int* __restrict__ endA)
{
    __shared__ int deg[BNODES];
    __shared__ int off[BNODES];
    __shared__ unsigned emaxL[BNODES];
    __shared__ int ssum[BNODES];

    const int b = blockIdx.x;
    const int t = threadIdx.x;
    const int cnt = bucket_cursor[b];
    const unsigned long long* eb = ebuf + (size_t)b * BCAP;
    unsigned long long* pb = perm + (size_t)b * BCAP;

    if (t < BNODES) { deg[t] = 0; emaxL[t] = ENC_NEG_INF; }
    __syncthreads();

    // pass A: load edges to registers, degree histogram + rank + segment max
    unsigned long long pv[MAXE];
    int rk[MAXE];
    #pragma unroll
    for (int k = 0; k < MAXE; ++k) {
        int i = t + k * 256;
        if (i < cnt) {
            unsigned long long v = eb[i];
            int ld = (int)(v & (BNODES - 1));
            unsigned e32 = (unsigned)(v >> 32);
            unsigned enc = (e32 & 0x80000000u) ? ~e32 : (e32 | 0x80000000u);
            rk[k] = atomicAdd(&deg[ld], 1);
            atomicMax(&emaxL[ld], enc);
            pv[k] = v;
        }
    }
    __syncthreads();

    // exclusive scan of padded degrees (BNODES entries, Hillis-Steele)
    int d = 0, pd = 0;
    if (t < BNODES) {
        d  = deg[t];
        pd = (d + 3) & ~3;
        ssum[t] = pd;
    }
    __syncthreads();
    #pragma unroll
    for (int o = 1; o < BNODES; o <<= 1) {
        int v = 0;
        if (t >= o && t < BNODES) v = ssum[t - o];
        __syncthreads();
        if (t < BNODES) ssum[t] += v;
        __syncthreads();
    }
    if (t < BNODES) off[t] = ssum[t] - pd;
    __syncthreads();

    // pass B: w = exp(e - mx); place (w,src) at off[ld] + rank (from registers)
    #pragma unroll
    for (int k = 0; k < MAXE; ++k) {
        int i = t + k * 256;
        if (i < cnt) {
            unsigned long long v = pv[k];
            int ld = (int)(v & (BNODES - 1));
            unsigned s = (unsigned)((v >> BSHIFT) & 0x1FFFFu);
            float e = __uint_as_float((unsigned)(v >> 32));
            unsigned u = emaxL[ld];
            float mx = (u & 0x80000000u) ? __uint_as_float(u ^ 0x80000000u)
                                         : __uint_as_float(~u);
            float w = __expf(e - mx);
            pb[off[ld] + rk[k]] = ((unsigned long long)__float_as_uint(w) << 32) | s;
        }
    }

    // pass C: dense per-node ranges + zero-weight pad fill (disjoint from pass B slots)
    if (t < BNODES) {
        int n = b * BNODES + t;
        if (n < N_NODES) {
            int o  = off[t];
            int gb = b * BCAP + o;
            begA[n] = gb;
            endA[n] = gb + pd;
            for (int j = o + d; j < o + pd; ++j) pb[j] = 0ull;   // w=0, src=0
        }
    }
}

// ---------------- weighted gather; denom summed inline ----------------
__global__ __launch_bounds__(256) void node_pass_k(
    const int* __restrict__ begA, const int* __restrict__ endA,
    const unsigned long long* __restrict__ perm,
    const unsigned* __restrict__ z16, float* __restrict__ out)
{
    int n    = (blockIdx.x * blockDim.x + threadIdx.x) >> 6;
    int lane = threadIdx.x & 63;
    if (n >= N_NODES) return;
    int beg = begA[n], end = endA[n];

    float acc0 = 0.0f, acc1 = 0.0f;
    if (end > beg) {
        float dsum = 0.0f;
        const uint4* pp = (const uint4*)perm;   // {src0,w0,src1,w1}
        #pragma unroll 2
        for (int i = (beg >> 2); i < (end >> 2); ++i) {
            uint4 pA = pp[2 * i];
            uint4 pB = pp[2 * i + 1];
            unsigned q0 = z16[(size_t)pA.x * 64 + lane];
            unsigned q1 = z16[(size_t)pA.z * 64 + lane];
            unsigned q2 = z16[(size_t)pB.x * 64 + lane];
            unsigned q3 = z16[(size_t)pB.z * 64 + lane];
            float w0 = __uint_as_float(pA.y);
            float w1 = __uint_as_float(pA.w);
            float w2 = __uint_as_float(pB.y);
            float w3 = __uint_as_float(pB.w);
            acc0 += w0 * __uint_as_float(q0 << 16)
                  + w1 * __uint_as_float(q1 << 16)
                  + w2 * __uint_as_float(q2 << 16)
                  + w3 * __uint_as_float(q3 << 16);
            acc1 += w0 * __uint_as_float(q0 & 0xFFFF0000u)
                  + w1 * __uint_as_float(q1 & 0xFFFF0000u)
                  + w2 * __uint_as_float(q2 & 0xFFFF0000u)
                  + w3 * __uint_as_float(q3 & 0xFFFF0000u);
            dsum += w0 + w1 + w2 + w3;
        }
        // at least one real edge in range => dsum >= exp(emax-emax) = 1
        float inv = 1.0f / dsum;
        acc0 *= inv; acc1 *= inv;
    }
    *(float2*)&out[(size_t)n * OUT_DIM + lane * 2] = make_float2(acc0, acc1);
}

// ---------------- launch ----------------
extern "C" void kernel_launch(void* const* d_in, const int* in_sizes, int n_in,
                              void* d_out, int out_size, void* d_ws, size_t ws_size,
                              hipStream_t stream)
{
    (void)in_sizes; (void)n_in; (void)out_size; (void)ws_size;
    const float* h = (const float*)d_in[0];
    const float* W = (const float*)d_in[1];
    const float* a = (const float*)d_in[2];
    const int* src = (const int*)d_in[3];
    const int* dst = (const int*)d_in[4];
    float* out = (float*)d_out;

    char* ws = (char*)d_ws;
    size_t off = 0;
    auto alloc = [&](size_t bytes) -> char* {
        char* p = ws + off;
        off += (bytes + 255) & ~(size_t)255;
        return p;
    };
    unsigned short* z16  = (unsigned short*)alloc((size_t)N_NODES * OUT_DIM * 2);
    unsigned short* w16s = (unsigned short*)alloc((size_t)IN_DIM * OUT_DIM * 2);
    float*    el        = (float*)   alloc((size_t)N_NODES * 4);
    float*    er        = (float*)   alloc((size_t)N_NODES * 4);
    int*      bucket_cursor = (int*) alloc((size_t)NBUCK * 4);
    unsigned long long* ebuf = (unsigned long long*)alloc((size_t)NBUCK * BCAP * 8);
    unsigned long long* perm = (unsigned long long*)alloc((size_t)NBUCK * BCAP * 8);
    int*      begA      = (int*)     alloc((size_t)N_NODES * 4);
    int*      endA      = (int*)     alloc((size_t)N_NODES * 4);

    w16s_k<<<(IN_DIM * OUT_DIM + 255) / 256, 256, 0, stream>>>(W, w16s, bucket_cursor);
    gemm_z_k<<<(N_NODES + 63) / 64, 256, 0, stream>>>(h, w16s, a, z16, el, er);
    partition_k<<<(N_EDGES + EPB - 1) / EPB, 256, 0, stream>>>(src, dst, el, er,
                                                               bucket_cursor, ebuf);
    bucket_k<<<NBUCK, 256, 0, stream>>>(bucket_cursor, ebuf, perm, begA, endA);
    node_pass_k<<<(N_NODES * 64 + 255) / 256, 256, 0, stream>>>(begA, endA, perm,
                                                                (const unsigned*)z16, out);
}